// Round 6
// baseline (562.903 us; speedup 1.0000x reference)
//
#include <hip/hip_runtime.h>
#include <hip/hip_bf16.h>

#define N_NODES 100000
#define N_EDGES 1600000
#define DIM 128
#define SCAN_CHUNK 1024

typedef __attribute__((ext_vector_type(8))) short bf16x8;
typedef __attribute__((ext_vector_type(4))) float f32x4;
typedef __attribute__((ext_vector_type(4))) short bf16x4;

// fp32 -> bf16 elementwise (RNE), 4 elems/thread
__global__ void cvt_kernel(const float* __restrict__ in, __hip_bfloat16* __restrict__ out, int n4) {
    int i = blockIdx.x * blockDim.x + threadIdx.x;
    if (i < n4) {
        f32x4 v = ((const f32x4*)in)[i];
        bf16x4 o;
        o.x = (short)__bfloat16_as_ushort(__float2bfloat16(v.x));
        o.y = (short)__bfloat16_as_ushort(__float2bfloat16(v.y));
        o.z = (short)__bfloat16_as_ushort(__float2bfloat16(v.z));
        o.w = (short)__bfloat16_as_ushort(__float2bfloat16(v.w));
        ((bf16x4*)out)[i] = o;
    }
}

// both 128x128 weights in one launch
__global__ void cvtw_kernel(const float* __restrict__ w1, const float* __restrict__ w2,
                            __hip_bfloat16* __restrict__ w1b, __hip_bfloat16* __restrict__ w2b) {
    int i = blockIdx.x * blockDim.x + threadIdx.x;
    if (i < DIM * DIM) {
        w1b[i] = __float2bfloat16(w1[i]);
        w2b[i] = __float2bfloat16(w2[i]);
    }
}

// degree count + per-edge within-dst rank. 8 edges per thread, batched:
// 8 independent dst loads -> 8 outstanding atomicAdds -> 8 coalesced rank stores.
#define DR_UNROLL 8
__global__ void degrank_kernel(const int* __restrict__ dst, int* __restrict__ deg,
                               int* __restrict__ rank) {
    int tid = blockIdx.x * blockDim.x + threadIdx.x;
    int nthreads = gridDim.x * blockDim.x;
    int d_[DR_UNROLL], r_[DR_UNROLL];
#pragma unroll
    for (int k = 0; k < DR_UNROLL; k++) {
        int e = tid + k * nthreads;
        d_[k] = (e < N_EDGES) ? dst[e] : -1;
    }
#pragma unroll
    for (int k = 0; k < DR_UNROLL; k++)
        if (d_[k] >= 0) r_[k] = atomicAdd(&deg[d_[k]], 1);
#pragma unroll
    for (int k = 0; k < DR_UNROLL; k++) {
        int e = tid + k * nthreads;
        if (e < N_EDGES) rank[e] = r_[k];
    }
}

// per-block partial sums over chunks of 1024
__global__ void scan1_kernel(const int* __restrict__ deg, int* __restrict__ bsum) {
    __shared__ int s[256];
    int t = threadIdx.x;
    int base = blockIdx.x * SCAN_CHUNK + t * 4;
    int v = 0;
    for (int k = 0; k < 4; k++) { int i = base + k; if (i < N_NODES) v += deg[i]; }
    s[t] = v;
    __syncthreads();
    for (int off = 128; off > 0; off >>= 1) { if (t < off) s[t] += s[t + off]; __syncthreads(); }
    if (t == 0) bsum[blockIdx.x] = s[0];
}

__global__ void scan2_kernel(const int* __restrict__ bsum, int* __restrict__ bscan,
                             int* __restrict__ row_start, int nb) {
    if (threadIdx.x == 0) {
        int run = 0;
        for (int b = 0; b < nb; b++) { bscan[b] = run; run += bsum[b]; }
        row_start[N_NODES] = run;
    }
}

__global__ void scan3_kernel(const int* __restrict__ deg, const int* __restrict__ bscan,
                             int* __restrict__ row_start) {
    __shared__ int s[256];
    int t = threadIdx.x;
    int base = blockIdx.x * SCAN_CHUNK + t * 4;
    int v[4]; int tot = 0;
    for (int k = 0; k < 4; k++) { int i = base + k; v[k] = (i < N_NODES) ? deg[i] : 0; tot += v[k]; }
    s[t] = tot;
    __syncthreads();
    for (int off = 1; off < 256; off <<= 1) {
        int a = (t >= off) ? s[t - off] : 0;
        __syncthreads();
        s[t] += a;
        __syncthreads();
    }
    int run = s[t] - tot + bscan[blockIdx.x];  // exclusive prefix for this thread
    for (int k = 0; k < 4; k++) {
        int i = base + k;
        if (i < N_NODES) row_start[i] = run;
        run += v[k];
    }
}

// atomic-free scatter, 4 edges per thread batched for ILP:
// coalesced loads -> 4 independent row_start gathers -> 4 fire-and-forget 8B stores
#define FI_UNROLL 4
__global__ void fill_kernel(const int* __restrict__ src, const int* __restrict__ dst,
                            const float* __restrict__ ew, const int* __restrict__ rank,
                            const int* __restrict__ row_start, int2* __restrict__ sw_s) {
    int tid = blockIdx.x * blockDim.x + threadIdx.x;
    int nthreads = gridDim.x * blockDim.x;
    int d_[FI_UNROLL], r_[FI_UNROLL], s_[FI_UNROLL], w_[FI_UNROLL], rs_[FI_UNROLL];
#pragma unroll
    for (int k = 0; k < FI_UNROLL; k++) {
        int e = tid + k * nthreads;
        if (e < N_EDGES) {
            d_[k] = dst[e]; r_[k] = rank[e]; s_[k] = src[e]; w_[k] = __float_as_int(ew[e]);
        } else d_[k] = -1;
    }
#pragma unroll
    for (int k = 0; k < FI_UNROLL; k++)
        if (d_[k] >= 0) rs_[k] = row_start[d_[k]];
#pragma unroll
    for (int k = 0; k < FI_UNROLL; k++)
        if (d_[k] >= 0) sw_s[rs_[k] + r_[k]] = make_int2(s_[k], w_[k]);
}

// one WAVE per node (4 nodes / 256-thr block); each lane owns 2 adjacent channels
// (bf16x2 = 4B gather per lane -> 256B/wave transaction). Wave-synchronous LDS
// staging: no __syncthreads (waves have independent, divergent degree loops).
__global__ __launch_bounds__(256) void agg_kernel(const __hip_bfloat16* __restrict__ x,
                                                  const int* __restrict__ row_start,
                                                  const int2* __restrict__ sw_s,
                                                  const float* __restrict__ eps, int li,
                                                  __hip_bfloat16* __restrict__ h) {
    __shared__ int2 s_sw[4][64];
    int wv = threadIdx.x >> 6;
    int lane = threadIdx.x & 63;
    int n = blockIdx.x * 4 + wv;
    if (n >= N_NODES) return;
    int beg = row_start[n], end = row_start[n + 1];
    const __hip_bfloat162* xp = (const __hip_bfloat162*)x;  // row n: 64 x bf16x2
    float ax = 0.f, ay = 0.f;
    for (int base = beg; base < end; base += 64) {
        int cnt = min(64, end - base);
        if (lane < cnt) s_sw[wv][lane] = sw_s[base + lane];
        // wave-synchronous: ds_write completed for all 64 lockstep lanes before reads
        asm volatile("s_waitcnt lgkmcnt(0)" ::: "memory");
        int i = 0;
        for (; i + 4 <= cnt; i += 4) {
            int2 e0 = s_sw[wv][i], e1 = s_sw[wv][i + 1], e2 = s_sw[wv][i + 2], e3 = s_sw[wv][i + 3];
            __hip_bfloat162 v0 = xp[(size_t)e0.x * 64 + lane];
            __hip_bfloat162 v1 = xp[(size_t)e1.x * 64 + lane];
            __hip_bfloat162 v2 = xp[(size_t)e2.x * 64 + lane];
            __hip_bfloat162 v3 = xp[(size_t)e3.x * 64 + lane];
            float w0 = __int_as_float(e0.y), w1 = __int_as_float(e1.y);
            float w2 = __int_as_float(e2.y), w3 = __int_as_float(e3.y);
            ax += __bfloat162float(v0.x) * w0 + __bfloat162float(v1.x) * w1
                + __bfloat162float(v2.x) * w2 + __bfloat162float(v3.x) * w3;
            ay += __bfloat162float(v0.y) * w0 + __bfloat162float(v1.y) * w1
                + __bfloat162float(v2.y) * w2 + __bfloat162float(v3.y) * w3;
        }
        for (; i < cnt; i++) {
            int2 e = s_sw[wv][i];
            __hip_bfloat162 v = xp[(size_t)e.x * 64 + lane];
            float w = __int_as_float(e.y);
            ax += __bfloat162float(v.x) * w;
            ay += __bfloat162float(v.y) * w;
        }
        asm volatile("" ::: "memory");  // keep next iter's ds_write below these reads
    }
    int degn = end - beg;
    float dinv = degn > 0 ? 1.0f / (float)degn : 0.0f;
    float ep = 1.0f + eps[li];
    __hip_bfloat162 xs = xp[(size_t)n * 64 + lane];
    float vx = ep * __bfloat162float(xs.x) + ax * dinv;
    float vy = ep * __bfloat162float(xs.y) + ay * dinv;
    __hip_bfloat162 o;
    o.x = __float2bfloat16(vx);
    o.y = __float2bfloat16(vy);
    ((__hip_bfloat162*)h)[(size_t)n * 64 + lane] = o;
}

// out[n][j] = sum_d h[n][d] * W[j][d] + b[j]; optional relu / zero row0 / bf16-or-fp32 out.
// block = 4 waves; wave handles 16 rows x 128 cols, K=128
template <int RELU, int ZERO0, int OUTBF>
__global__ __launch_bounds__(256) void gemm_kernel(const __hip_bfloat16* __restrict__ A,
                                                   const __hip_bfloat16* __restrict__ W,
                                                   const float* __restrict__ bias,
                                                   void* __restrict__ outv) {
    int wave = threadIdx.x >> 6;
    int lane = threadIdx.x & 63;
    int row0 = blockIdx.x * 64 + wave * 16;
    int lr = lane & 15;   // row within A-tile / row of W
    int kg = lane >> 4;   // k-subgroup (8 elements each)

    int arow = row0 + lr;
    if (arow > N_NODES - 1) arow = N_NODES - 1;
    const short* Ap = (const short*)A + (size_t)arow * DIM + kg * 8;
    bf16x8 a[4];
#pragma unroll
    for (int k = 0; k < 4; k++) a[k] = *(const bf16x8*)(Ap + k * 32);

    f32x4 acc[8];
#pragma unroll
    for (int jt = 0; jt < 8; jt++) {
        const short* Wp = (const short*)W + (size_t)(jt * 16 + lr) * DIM + kg * 8;
        f32x4 c = {0.f, 0.f, 0.f, 0.f};
#pragma unroll
        for (int k = 0; k < 4; k++) {
            bf16x8 b = *(const bf16x8*)(Wp + k * 32);
            c = __builtin_amdgcn_mfma_f32_16x16x32_bf16(a[k], b, c, 0, 0, 0);
        }
        acc[jt] = c;
    }

    int colb = lane & 15;
    int rb = (lane >> 4) * 4;
#pragma unroll
    for (int jt = 0; jt < 8; jt++) {
        int col = jt * 16 + colb;
        float bv = bias[col];
#pragma unroll
        for (int r = 0; r < 4; r++) {
            int grow = row0 + rb + r;
            if (grow < N_NODES) {
                float v = acc[jt][r] + bv;
                if (RELU) v = fmaxf(v, 0.f);
                if (ZERO0 && grow == 0) v = 0.f;
                if (OUTBF)
                    ((__hip_bfloat16*)outv)[(size_t)grow * DIM + col] = __float2bfloat16(v);
                else
                    ((float*)outv)[(size_t)grow * DIM + col] = v;
            }
        }
    }
}

extern "C" void kernel_launch(void* const* d_in, const int* in_sizes, int n_in,
                              void* d_out, int out_size, void* d_ws, size_t ws_size,
                              hipStream_t stream) {
    const float* emb = (const float*)d_in[0];
    const float* w1  = (const float*)d_in[1];
    const float* b1  = (const float*)d_in[2];
    const float* w2  = (const float*)d_in[3];
    const float* b2  = (const float*)d_in[4];
    const float* eps = (const float*)d_in[5];
    const float* ew  = (const float*)d_in[6];
    const int* src   = (const int*)d_in[7];
    const int* dst   = (const int*)d_in[8];
    float* out = (float*)d_out;

    char* base = (char*)d_ws;
    size_t off = 0;
    auto alloc = [&](size_t bytes) -> char* {
        char* p = base + off;
        off += (bytes + 255) & ~(size_t)255;
        return p;
    };
    int* deg            = (int*)alloc((size_t)N_NODES * 4);
    int* row_start      = (int*)alloc((size_t)(N_NODES + 1) * 4);
    int* rank           = (int*)alloc((size_t)N_EDGES * 4);
    int* bsum           = (int*)alloc(128 * 4);
    int* bscan          = (int*)alloc(128 * 4);
    int2* sw_s          = (int2*)alloc((size_t)N_EDGES * 8);
    __hip_bfloat16* h   = (__hip_bfloat16*)alloc((size_t)N_NODES * DIM * 2);
    __hip_bfloat16* xb  = (__hip_bfloat16*)alloc((size_t)N_NODES * DIM * 2);
    __hip_bfloat16* embb= (__hip_bfloat16*)alloc((size_t)N_NODES * DIM * 2);
    __hip_bfloat16* w1b = (__hip_bfloat16*)alloc(DIM * DIM * 2);
    __hip_bfloat16* w2b = (__hip_bfloat16*)alloc(DIM * DIM * 2);

    hipMemsetAsync(deg, 0, (size_t)N_NODES * 4, stream);

    // dtype conversions
    cvt_kernel<<<(N_NODES * DIM / 4 + 255) / 256, 256, 0, stream>>>(emb, embb, N_NODES * DIM / 4);
    cvtw_kernel<<<(DIM * DIM + 255) / 256, 256, 0, stream>>>(w1, w2, w1b, w2b);

    // CSR build (atomic-free scatter via precomputed ranks)
    {
        int nthreads = ((N_EDGES + DR_UNROLL - 1) / DR_UNROLL + 255) & ~255;
        degrank_kernel<<<nthreads / 256, 256, 0, stream>>>(dst, deg, rank);
    }
    int nb = (N_NODES + SCAN_CHUNK - 1) / SCAN_CHUNK;
    scan1_kernel<<<nb, 256, 0, stream>>>(deg, bsum);
    scan2_kernel<<<1, 64, 0, stream>>>(bsum, bscan, row_start, nb);
    scan3_kernel<<<nb, 256, 0, stream>>>(deg, bscan, row_start);
    {
        int nthreads = ((N_EDGES + FI_UNROLL - 1) / FI_UNROLL + 255) & ~255;
        fill_kernel<<<nthreads / 256, 256, 0, stream>>>(src, dst, ew, rank, row_start, sw_s);
    }

    int gemm_blocks = (N_NODES + 63) / 64;
    int agg_blocks = (N_NODES + 3) / 4;
    agg_kernel<<<agg_blocks, 256, 0, stream>>>(embb, row_start, sw_s, eps, 0, h);
    gemm_kernel<1, 0, 1><<<gemm_blocks, 256, 0, stream>>>(h, w1b, b1, xb);
    agg_kernel<<<agg_blocks, 256, 0, stream>>>(xb, row_start, sw_s, eps, 1, h);
    gemm_kernel<1, 0, 1><<<gemm_blocks, 256, 0, stream>>>(h, w2b, b2, xb);
    agg_kernel<<<agg_blocks, 256, 0, stream>>>(xb, row_start, sw_s, eps, 2, h);
    gemm_kernel<0, 1, 0><<<gemm_blocks, 256, 0, stream>>>(h, w2b, b2, out);
}